// Round 2
// baseline (144.616 us; speedup 1.0000x reference)
//
#include <hip/hip_runtime.h>

// Rowwise cosine similarity: out[r] = dot(a_r,b_r) * rsqrt(max(|a_r|^2,eps)) * rsqrt(max(|b_r|^2,eps))
// a, b: [16, 4096, 256] f32 contiguous -> 65536 rows of 256 floats.
//
// v3: streaming-reduce shape (BabelStream-dot style).
//  Theory from r1 post-mortem: v1/v2 tie at 3.15 TB/s because every wave
//  issues one load burst then stops issuing forever (reduce -> store -> exit);
//  average outstanding-lines/CU sawtooths instead of holding steady.
//  Fix: long-lived waves that keep issuing loads the whole kernel:
//   - 1024 blocks x 4 waves; each wave owns 16 CONTIGUOUS rows (16 KB a + 16 KB b).
//   - 4 chunks of 4 rows; register double-buffer: chunk c+1's 8 dwordx4 loads
//     are issued BEFORE chunk c is consumed, so the wave always has 8-16 loads
//     in flight until the final chunk.
//   - 16 lanes per row -> 4-step butterfly per chunk (independent chains for
//     the 4 rows overlap); all buffer indices compile-time (full unroll).

#define D4         64          // float4s per row
#define EPS        1e-12f
#define LANES_ROW  16          // lanes cooperating on one row
#define CHUNK_ROWS 4           // rows per chunk (64 / LANES_ROW)
#define F4_CHUNK   4           // load instructions per array per chunk
#define NCHUNK     4           // chunks per wave -> 16 rows per wave
#define ROWS_WAVE  (CHUNK_ROWS * NCHUNK)
#define WAVES_BLK  4

__global__ __launch_bounds__(256) void cosine_rows_kernel(
    const float* __restrict__ a,
    const float* __restrict__ b,
    float* __restrict__ out,
    int n_rows)
{
    const int lane = threadIdx.x & 63;
    const int wave = threadIdx.x >> 6;
    const int g    = lane >> 4;        // row within chunk (0..3)
    const int s    = lane & 15;        // sublane within row (0..15)

    const int wave_id = blockIdx.x * WAVES_BLK + wave;
    const int row0    = wave_id * ROWS_WAVE;
    if (row0 >= n_rows) return;

    // lane base: row (row0+g), column s*4 floats
    const float4* A = reinterpret_cast<const float4*>(a) + (size_t)(row0 + g) * D4 + s;
    const float4* B = reinterpret_cast<const float4*>(b) + (size_t)(row0 + g) * D4 + s;
    // chunk c offset: c*CHUNK_ROWS rows = c*256 float4s; instr k: +k*16 float4s

    float4 av[2][F4_CHUNK], bv[2][F4_CHUNK];

    // prologue: issue chunk 0 loads
    #pragma unroll
    for (int k = 0; k < F4_CHUNK; ++k) {
        av[0][k] = A[k * LANES_ROW];
        bv[0][k] = B[k * LANES_ROW];
    }

    #pragma unroll
    for (int c = 0; c < NCHUNK; ++c) {
        const int cur = c & 1;
        const int nxt = cur ^ 1;

        // issue next chunk's loads before consuming current (keeps the wave
        // issuing; compiler waits only on the current chunk's vmcnt slice)
        if (c < NCHUNK - 1) {
            #pragma unroll
            for (int k = 0; k < F4_CHUNK; ++k) {
                av[nxt][k] = A[(c + 1) * CHUNK_ROWS * D4 + k * LANES_ROW];
                bv[nxt][k] = B[(c + 1) * CHUNK_ROWS * D4 + k * LANES_ROW];
            }
        }

        float sa = 0.f, sb = 0.f, sab = 0.f;
        #pragma unroll
        for (int k = 0; k < F4_CHUNK; ++k) {
            float4 x = av[cur][k], y = bv[cur][k];
            sa  += x.x * x.x + x.y * x.y + x.z * x.z + x.w * x.w;
            sb  += y.x * y.x + y.y * y.y + y.z * y.z + y.w * y.w;
            sab += x.x * y.x + x.y * y.y + x.z * y.z + x.w * y.w;
        }

        // 4-step butterfly within the 16-lane row group (4 independent chains)
        #pragma unroll
        for (int off = 1; off < LANES_ROW; off <<= 1) {
            sa  += __shfl_xor(sa,  off, 64);
            sb  += __shfl_xor(sb,  off, 64);
            sab += __shfl_xor(sab, off, 64);
        }

        if (s == 0) {
            const int r = row0 + c * CHUNK_ROWS + g;
            if (r < n_rows)
                out[r] = sab * rsqrtf(fmaxf(sa, EPS)) * rsqrtf(fmaxf(sb, EPS));
        }
    }
}

extern "C" void kernel_launch(void* const* d_in, const int* in_sizes, int n_in,
                              void* d_out, int out_size, void* d_ws, size_t ws_size,
                              hipStream_t stream)
{
    const float* a = (const float*)d_in[0];
    const float* b = (const float*)d_in[1];
    float* out = (float*)d_out;

    const int n_rows = out_size;                         // 16 * 4096 = 65536
    const int rows_per_block = WAVES_BLK * ROWS_WAVE;    // 64
    const int grid = (n_rows + rows_per_block - 1) / rows_per_block;  // 1024

    cosine_rows_kernel<<<grid, 256, 0, stream>>>(a, b, out, n_rows);
}

// Round 3
// 134.856 us; speedup vs baseline: 1.0724x; 1.0724x over previous
//
#include <hip/hip_runtime.h>

// Rowwise cosine similarity: out[r] = dot(a_r,b_r) * rsqrt(max(|a_r|^2,eps)) * rsqrt(max(|b_r|^2,eps))
// a, b: [16, 4096, 256] f32 contiguous -> 65536 rows of 256 floats.
//
// v4: v2 shape + NON-TEMPORAL loads.
//  r2 finding: v1/v2/v3 (wildly different wave shapes / MLP / occupancy) all
//  tie at ~3.2 TB/s effective; FETCH_SIZE pinned at half the input (other
//  half = Infinity Cache hits). Theory: harness poison-fills leave 256 MiB
//  of DIRTY lines in MALL; our read-misses allocate and force dirty
//  writebacks to HBM (invisible to TCC WRITE_SIZE) -> HBM channels ~2x
//  busier than the visible 67 MB fetch. Fix: nt loads (no allocation on
//  miss -> no evictions -> no hidden writebacks). Hits still hit.
//
//  Shape (from v2, best-tied): 8 rows/wave, 8 lanes/row, 8 float4/lane;
//  each 8-lane group covers one 128B line per unrolled step; 3-step
//  butterfly per 8 rows.

#define D4         64          // float4s per row
#define EPS        1e-12f
#define LANES_ROW  8
#define ROWS_WAVE  8
#define F4_LANE    8
#define WAVES_BLK  4

typedef float f32x4 __attribute__((ext_vector_type(4)));

__global__ __launch_bounds__(256) void cosine_rows_kernel(
    const float* __restrict__ a,
    const float* __restrict__ b,
    float* __restrict__ out,
    int n_rows)
{
    const int lane = threadIdx.x & 63;
    const int wave = threadIdx.x >> 6;
    const int g    = lane >> 3;        // row index within this wave's batch
    const int s    = lane & 7;         // sublane within the row

    const int row = (blockIdx.x * WAVES_BLK + wave) * ROWS_WAVE + g;
    if (row >= n_rows) return;

    const f32x4* A = reinterpret_cast<const f32x4*>(a) + (size_t)row * D4 + s;
    const f32x4* B = reinterpret_cast<const f32x4*>(b) + (size_t)row * D4 + s;

    f32x4 av[F4_LANE], bv[F4_LANE];
    #pragma unroll
    for (int k = 0; k < F4_LANE; ++k) {
        av[k] = __builtin_nontemporal_load(A + k * LANES_ROW);
        bv[k] = __builtin_nontemporal_load(B + k * LANES_ROW);
    }

    float sa = 0.f, sb = 0.f, sab = 0.f;
    #pragma unroll
    for (int k = 0; k < F4_LANE; ++k) {
        f32x4 x = av[k], y = bv[k];
        sa  += x.x * x.x + x.y * x.y + x.z * x.z + x.w * x.w;
        sb  += y.x * y.x + y.y * y.y + y.z * y.z + y.w * y.w;
        sab += x.x * y.x + x.y * y.y + x.z * y.z + x.w * y.w;
    }

    // 3-step butterfly within the 8-lane group (groups are xor-aligned).
    #pragma unroll
    for (int off = 1; off < LANES_ROW; off <<= 1) {
        sa  += __shfl_xor(sa,  off, 64);
        sb  += __shfl_xor(sb,  off, 64);
        sab += __shfl_xor(sab, off, 64);
    }

    if (s == 0) {
        out[row] = sab * rsqrtf(fmaxf(sa, EPS)) * rsqrtf(fmaxf(sb, EPS));
    }
}

extern "C" void kernel_launch(void* const* d_in, const int* in_sizes, int n_in,
                              void* d_out, int out_size, void* d_ws, size_t ws_size,
                              hipStream_t stream)
{
    const float* a = (const float*)d_in[0];
    const float* b = (const float*)d_in[1];
    float* out = (float*)d_out;

    const int n_rows = out_size;                        // 16 * 4096 = 65536
    const int rows_per_block = WAVES_BLK * ROWS_WAVE;   // 32
    const int grid = (n_rows + rows_per_block - 1) / rows_per_block;

    cosine_rows_kernel<<<grid, 256, 0, stream>>>(a, b, out, n_rows);
}